// Round 4
// baseline (112.677 us; speedup 1.0000x reference)
//
#include <hip/hip_runtime.h>
#include <math.h>

// d_in order: X[300000,256] f32, y[300000,1] f32, Z[1000,8] f32,
//             beta_w[1,256] f32, gamma_w[1,8] f32, theta[1] f32
// ws layout: [0..7] double acc_sum; [8..11] uint counter.  (zeroed each call)

typedef float f32x4 __attribute__((ext_vector_type(4)));
#define NT 256

__global__ __launch_bounds__(256) void k_all(const f32x4* __restrict__ X4,
                                             const float* __restrict__ y,
                                             const f32x4* __restrict__ beta4,
                                             const float* __restrict__ Z,
                                             const float* __restrict__ gamma_w,
                                             const float* __restrict__ theta,
                                             double* __restrict__ acc_sum,
                                             unsigned int* __restrict__ acc_cnt,
                                             float* __restrict__ out,
                                             int V, int n_study) {
    const int t    = threadIdx.x;
    const int lane = t & 63;
    const int wib  = t >> 6;
    const int wave = blockIdx.x * 4 + wib;
    const int row0 = wave << 6;
    const bool fullTile = (row0 + 64 <= V);

    const int sub = lane >> 3;   // row-in-pass (0..7)
    const int ch  = lane & 7;    // chunk group (0..7)

    __shared__ double sred[8];
    __shared__ float  sL[32];
    __shared__ double bl[4];

    // ---- prefetch pass 0 of this wave's tile (overlaps the scalar phase) ----
    const f32x4* Xb = X4 + (size_t)row0 * 64;
    f32x4 xa[8], xn[8];
    if (fullTile) {
#pragma unroll
        for (int k = 0; k < 8; ++k)
            xa[k] = __builtin_nontemporal_load(Xb + (size_t)sub * 64 + ch + 8 * k);
    }

    // ---- block-redundant scalar phase (cheap: f32 expf, f64 sums only) ----
    double s1 = 0.0, s2 = 0.0;
    {
        float g[8];
#pragma unroll
        for (int j = 0; j < 8; ++j) g[j] = gamma_w[j];
        for (int s = t; s < n_study; s += NT) {
            float dz = 0.f;
#pragma unroll
            for (int j = 0; j < 8; ++j) dz = fmaf(Z[s * 8 + j], g[j], dz);
            float mz = expf(dz);
            s1 += (double)mz;
            s2 += (double)(mz * mz);
        }
#pragma unroll
        for (int m = 32; m; m >>= 1) {
            s1 += __shfl_xor(s1, m, 64);
            s2 += __shfl_xor(s2, m, 64);
        }
        if (lane == 0) { sred[2 * wib] = s1; sred[2 * wib + 1] = s2; }
    }
    __syncthreads();
    const double S1 = sred[0] + sred[2] + sred[4] + sred[6];
    const double S2 = sred[1] + sred[3] + sred[5] + sred[7];
    const float s1c = (float)S1, s2c = (float)S2;
    const float sig    = 1.f / (1.f + expf(-theta[0]));
    const float alphaf = fmaf(100.f * (float)n_study, sig, 1e-8f);
    const float vc = (s1c * s1c) / (alphaf * s2c);  // 1/est
    const float rc = vc * s1c * s1c / s2c;

    // ---- L[y] = lgamma(y+r)-lgamma(y+1)-lgamma(r) via parallel prefix scan ----
    if (t < 32) {
        float x = (t < 31) ? logf((rc + (float)t) / (float)(t + 1)) : 0.f;
        float S = x;
#pragma unroll
        for (int d = 1; d < 32; d <<= 1) {
            float v2 = __shfl_up(S, d, 32);
            S += (t >= d) ? v2 : 0.f;
        }
        sL[t] = S - x;  // exclusive scan
    }
    __syncthreads();

    // ---- main: 8 passes × 8 rows, 8 lanes per row ----
    double term = 0.0;
    if (fullTile) {
        f32x4 bf[8];
#pragma unroll
        for (int k = 0; k < 8; ++k) bf[k] = beta4[ch + 8 * k];
        float dmine = 0.f;
#pragma unroll
        for (int p = 0; p < 8; ++p) {
            if (p < 7) {
#pragma unroll
                for (int k = 0; k < 8; ++k)
                    xn[k] = __builtin_nontemporal_load(Xb + (size_t)(8 * (p + 1) + sub) * 64 + ch + 8 * k);
            }
            float dl = 0.f;
#pragma unroll
            for (int k = 0; k < 8; ++k)
                dl += fmaf(xa[k].x, bf[k].x,
                      fmaf(xa[k].y, bf[k].y,
                      fmaf(xa[k].z, bf[k].z, xa[k].w * bf[k].w)));
            // row sum across the 8 lanes sharing this row (3 swizzles)
            dl += __shfl_xor(dl, 1, 64);
            dl += __shfl_xor(dl, 2, 64);
            dl += __shfl_xor(dl, 4, 64);
            dmine = (ch == p) ? dl : dmine;   // lane owns row row0 + 8*ch + sub
#pragma unroll
            for (int k = 0; k < 8; ++k) xa[k] = xn[k];
        }
        const float yv = y[row0 + 8 * ch + sub];
        const float mu = expf(dmine);
        const float num = mu * mu * s2c;
        const float pp = num / fmaf(vc * s1c, mu, num);
        int yi = (int)yv; yi = yi < 0 ? 0 : (yi > 31 ? 31 : yi);
        term = (double)(sL[yi] + rc * log1pf(-pp) + yv * logf(pp));
    } else if (row0 < V) {  // tail wave (32 rows), serial per-row reduce
        const f32x4 b = beta4[lane];
        const int nrows = V - row0;
        float dmine = 0.f;
        for (int rr = 0; rr < nrows; ++rr) {
            f32x4 x = Xb[(size_t)rr * 64 + lane];
            float dd = fmaf(x.x, b.x, fmaf(x.y, b.y, fmaf(x.z, b.z, x.w * b.w)));
#pragma unroll
            for (int m = 32; m; m >>= 1) dd += __shfl_xor(dd, m, 64);
            if (lane == rr) dmine = dd;
        }
        if (lane < nrows) {
            const float yv = y[row0 + lane];
            const float mu = expf(dmine);
            const float num = mu * mu * s2c;
            const float pp = num / fmaf(vc * s1c, mu, num);
            int yi = (int)yv; yi = yi < 0 ? 0 : (yi > 31 ? 31 : yi);
            term = (double)(sL[yi] + rc * log1pf(-pp) + yv * logf(pp));
        }
    }

    // ---- wave + block reduce (f64), then device-level atomic finish ----
#pragma unroll
    for (int m = 32; m; m >>= 1) term += __shfl_xor(term, m, 64);
    if (lane == 0) bl[wib] = term;
    __syncthreads();
    if (t == 0) {
        double bs = bl[0] + bl[1] + bl[2] + bl[3];
        atomicAdd(acc_sum, bs);
        __threadfence();
        unsigned int old = atomicAdd(acc_cnt, 1u);
        if (old == gridDim.x - 1) {   // last block: all sums visible
            __threadfence();
            double tot = atomicAdd(acc_sum, 0.0);
            out[0] = -(float)tot;
        }
    }
}

extern "C" void kernel_launch(void* const* d_in, const int* in_sizes, int n_in,
                              void* d_out, int out_size, void* d_ws, size_t ws_size,
                              hipStream_t stream) {
    const float* X       = (const float*)d_in[0];
    const float* y       = (const float*)d_in[1];
    const float* Z       = (const float*)d_in[2];
    const float* beta_w  = (const float*)d_in[3];
    const float* gamma_w = (const float*)d_in[4];
    const float* theta   = (const float*)d_in[5];

    const int V       = in_sizes[0] / 256;
    const int n_study = in_sizes[2] / 8;

    double*       acc_sum = (double*)d_ws;
    unsigned int* acc_cnt = (unsigned int*)((char*)d_ws + 8);

    const int nwaves  = (V + 63) / 64;
    const int nblocks = (nwaves + 3) / 4;

    hipMemsetAsync(d_ws, 0, 16, stream);
    k_all<<<nblocks, 256, 0, stream>>>((const f32x4*)X, y, (const f32x4*)beta_w,
                                       Z, gamma_w, theta, acc_sum, acc_cnt,
                                       (float*)d_out, V, n_study);
}

// Round 5
// 66.417 us; speedup vs baseline: 1.6965x; 1.6965x over previous
//
#include <hip/hip_runtime.h>
#include <math.h>

// d_in order: X[300000,256] f32, y[300000,1] f32, Z[1000,8] f32,
//             beta_w[1,256] f32, gamma_w[1,8] f32, theta[1] f32
// ws layout: double partials[nwaves] at offset 0.

typedef float f32x4 __attribute__((ext_vector_type(4)));
#define NT 256

__global__ __launch_bounds__(256) void k_main(const f32x4* __restrict__ X4,
                                              const float* __restrict__ y,
                                              const f32x4* __restrict__ beta4,
                                              const f32x4* __restrict__ Z4,
                                              const f32x4* __restrict__ gamma4,
                                              const float* __restrict__ theta,
                                              double* __restrict__ partials,
                                              int V, int n_study) {
    const int lane = threadIdx.x & 63;
    const int wib  = threadIdx.x >> 6;
    const int wave = blockIdx.x * 4 + wib;
    const int row0 = wave << 6;
    if (row0 >= V) return;                       // whole wave exits together

    const int myrow = row0 + lane;
    const f32x4 b = beta4[lane];
    const f32x4* Xb = X4 + (size_t)row0 * 64;

    float dmine = 0.f;
    float yv = 0.f;

    if (row0 + 64 <= V) {
        // ---- memory-bound phase: 8 batches x 8 rows, double-buffered ----
        f32x4 xv[8], xn[8];
#pragma unroll
        for (int i = 0; i < 8; ++i)
            xv[i] = __builtin_nontemporal_load(Xb + i * 64 + lane);
#pragma unroll
        for (int bb = 0; bb < 8; ++bb) {
            if (bb < 7) {
#pragma unroll
                for (int i = 0; i < 8; ++i)
                    xn[i] = __builtin_nontemporal_load(Xb + ((bb + 1) * 8 + i) * 64 + lane);
            }
            float d[8];
#pragma unroll
            for (int i = 0; i < 8; ++i)
                d[i] = fmaf(xv[i].x, b.x, fmaf(xv[i].y, b.y, fmaf(xv[i].z, b.z, xv[i].w * b.w)));
            // 3-level pairwise transpose-tree; lane ends owning row row0+lane
#pragma unroll
            for (int s = 1; s < 8; s <<= 1) {
#pragma unroll
                for (int j = 0; j < 8; j += 2 * s) {
                    float ta = __shfl_xor(d[j], s, 64);
                    float tb = __shfl_xor(d[j + s], s, 64);
                    d[j] = (lane & s) ? (d[j + s] + tb) : (d[j] + ta);
                }
            }
            float rs = d[0];
            rs += __shfl_xor(rs, 8, 64);
            rs += __shfl_xor(rs, 16, 64);
            rs += __shfl_xor(rs, 32, 64);
            if ((lane >> 3) == bb) dmine = rs;
#pragma unroll
            for (int i = 0; i < 8; ++i) xv[i] = xn[i];
        }
        yv = y[myrow];
    } else {
        // tail wave (V-row0 rows)
        const int nrows = V - row0;
        for (int rr = 0; rr < nrows; ++rr) {
            f32x4 x = Xb[(size_t)rr * 64 + lane];
            float dd = fmaf(x.x, b.x, fmaf(x.y, b.y, fmaf(x.z, b.z, x.w * b.w)));
#pragma unroll
            for (int m = 32; m; m >>= 1) dd += __shfl_xor(dd, m, 64);
            if (lane == rr) dmine = dd;
        }
        if (lane < nrows) yv = y[myrow];
    }

    // ---- wave-local scalar phase (Z is L2-resident; overlaps other waves' X) ----
    double s1 = 0.0, s2 = 0.0;
    {
        const f32x4 g0 = gamma4[0], g1 = gamma4[1];
        for (int s = lane; s < n_study; s += 64) {
            f32x4 za = Z4[2 * s], zb = Z4[2 * s + 1];
            float dz = fmaf(za.x, g0.x, fmaf(za.y, g0.y, fmaf(za.z, g0.z, za.w * g0.w)));
            dz = fmaf(zb.x, g1.x, fmaf(zb.y, g1.y, fmaf(zb.z, g1.z, fmaf(zb.w, g1.w, dz))));
            float mz = expf(dz);
            s1 += (double)mz;
            s2 += (double)mz * (double)mz;
        }
#pragma unroll
        for (int m = 32; m; m >>= 1) {
            s1 += __shfl_xor(s1, m, 64);
            s2 += __shfl_xor(s2, m, 64);
        }
    }
    const double S1 = s1, S2 = s2;
    const double sig   = 1.0 / (1.0 + exp(-(double)theta[0]));
    const double alpha = 100.0 * (double)n_study * sig + 1e-8;
    const double est   = alpha * S2 / (S1 * S1);   // mean(voxel_sum_alpha), voxel-independent
    const double vv    = 1.0 / est;
    const double rr_   = vv * S1 * S1 / S2;
    const float s1c = (float)S1, s2c = (float)S2, vc = (float)vv, rc = (float)rr_;

    // ---- epilogue: per-lane NB log-likelihood term ----
    double term = 0.0;
    if (myrow < V) {
        const float mu  = expf(dmine);
        const float num = mu * mu * s2c;
        const float pp  = num / fmaf(vc * s1c, mu, num);
        float tl = rc * log1pf(-pp) + yv * logf(pp);
        const int yi = (int)yv;                     // y in {0..5}
        for (int k = 0; k < yi; ++k)                // lgamma(y+r)-lgamma(r)-lgamma(y+1)
            tl += logf((rc + (float)k) / (float)(k + 1));
        term = (double)tl;
    }

    // ---- wave reduce (f64), one partial per wave, no LDS/barriers ----
#pragma unroll
    for (int m = 32; m; m >>= 1) term += __shfl_xor(term, m, 64);
    if (lane == 0) partials[wave] = term;
}

__global__ __launch_bounds__(256) void k_reduce(const double* __restrict__ partials,
                                                int n, float* __restrict__ out) {
    __shared__ double red[NT];
    int t = threadIdx.x;
    double s = 0.0;
    for (int i = t; i < n; i += NT) s += partials[i];
    red[t] = s;
    __syncthreads();
    for (int off = NT / 2; off; off >>= 1) {
        if (t < off) red[t] += red[t + off];
        __syncthreads();
    }
    if (t == 0) out[0] = (float)(-red[0]);
}

extern "C" void kernel_launch(void* const* d_in, const int* in_sizes, int n_in,
                              void* d_out, int out_size, void* d_ws, size_t ws_size,
                              hipStream_t stream) {
    const float* X       = (const float*)d_in[0];
    const float* y       = (const float*)d_in[1];
    const float* Z       = (const float*)d_in[2];
    const float* beta_w  = (const float*)d_in[3];
    const float* gamma_w = (const float*)d_in[4];
    const float* theta   = (const float*)d_in[5];

    const int V       = in_sizes[0] / 256;
    const int n_study = in_sizes[2] / 8;

    double* partials = (double*)d_ws;

    const int nwaves  = (V + 63) / 64;
    const int nblocks = (nwaves + 3) / 4;

    k_main<<<nblocks, 256, 0, stream>>>((const f32x4*)X, y, (const f32x4*)beta_w,
                                        (const f32x4*)Z, (const f32x4*)gamma_w,
                                        theta, partials, V, n_study);
    k_reduce<<<1, 256, 0, stream>>>(partials, nwaves, (float*)d_out);
}